// Round 4
// baseline (382.475 us; speedup 1.0000x reference)
//
#include <hip/hip_runtime.h>
#include <hip/hip_cooperative_groups.h>
#include <math.h>

namespace cg = cooperative_groups;

// N=32768, M=4096, H=768 fp32.
// out[0..768)=fact_, out[768..1536)=elements_p_.
// Reassociation: (X@W)@y^T == X@(W@y^T) -> matvecs only, never a GEMM.
// R3 post-mortem: ~8.5us/graph-node launch gap dominated controllable time.
// R4: ONE cooperative kernel, 6 grid.sync()s replace 5 dispatch boundaries.

#define H 768
#define H4 192
#define PSTRIDE 772   // partial: [0]=m, [1]=L, [2..3]=pad, [4..772)=acc[768]
#define ACC_OFF 4
#define NB 256        // grid blocks (1/CU -> co-resident)
#define NT 512        // threads/block (8 waves)
#define NWV 8

struct SMem {
  float4 sacc[NWV][H4];  // 24.6 KB scratch, reused per phase
  float sred[16];
  float sfq[16];
};

__device__ __forceinline__ float wave_max(float x) {
#pragma unroll
  for (int o = 32; o; o >>= 1) x = fmaxf(x, __shfl_xor(x, o, 64));
  return x;
}
__device__ __forceinline__ float wave_sum(float x) {
#pragma unroll
  for (int o = 32; o; o >>= 1) x += __shfl_xor(x, o, 64);
  return x;
}
__device__ __forceinline__ float4 f4max(float4 a, float4 b) {
  return make_float4(fmaxf(a.x, b.x), fmaxf(a.y, b.y), fmaxf(a.z, b.z), fmaxf(a.w, b.w));
}

// online-softmax weighted row-sum over rows of X4; block partial -> part[blk].
__device__ void pass_phase(const float4* __restrict__ X4, const float* __restrict__ wvec,
                           float* __restrict__ part, int R, SMem& sm) {
  const int tid = threadIdx.x;
  const int lane = tid & 63;
  const int wv = tid >> 6;
  float4 wr[3];
#pragma unroll
  for (int j = 0; j < 3; ++j) wr[j] = ((const float4*)wvec)[lane + 64 * j];
  const int nw = NB * NWV;
  const int gw = blockIdx.x * NWV + wv;
  const int rpw = (R + nw - 1) / nw;
  const int r0 = gw * rpw;
  const int r1 = min(R, r0 + rpw);
  float mrun = -INFINITY, l = 0.f;
  float4 acc[3];
#pragma unroll
  for (int j = 0; j < 3; ++j) acc[j] = make_float4(0.f, 0.f, 0.f, 0.f);
  for (int r = r0; r < r1; ++r) {
    const float4* row = X4 + (size_t)r * H4;
    float4 x[3];
    float s = 0.f;
#pragma unroll
    for (int j = 0; j < 3; ++j) {
      x[j] = row[lane + 64 * j];
      s = fmaf(x[j].x, wr[j].x, s);
      s = fmaf(x[j].y, wr[j].y, s);
      s = fmaf(x[j].z, wr[j].z, s);
      s = fmaf(x[j].w, wr[j].w, s);
    }
#pragma unroll
    for (int o = 32; o; o >>= 1) s += __shfl_xor(s, o, 64);
    const float mn = fmaxf(mrun, s);
    const float esc = __expf(mrun - mn);  // exp(-inf)=0 on first row
    const float p = __expf(s - mn);
    l = fmaf(l, esc, p);
#pragma unroll
    for (int j = 0; j < 3; ++j) {
      acc[j].x = fmaf(acc[j].x, esc, p * x[j].x);
      acc[j].y = fmaf(acc[j].y, esc, p * x[j].y);
      acc[j].z = fmaf(acc[j].z, esc, p * x[j].z);
      acc[j].w = fmaf(acc[j].w, esc, p * x[j].w);
    }
    mrun = mn;
  }
  if (lane == 0) { sm.sred[wv] = mrun; sm.sred[8 + wv] = l; }
#pragma unroll
  for (int j = 0; j < 3; ++j) sm.sacc[wv][lane + 64 * j] = acc[j];
  __syncthreads();
  if (wv == 0) {
    float gm = -INFINITY;
#pragma unroll
    for (int w2 = 0; w2 < NWV; ++w2) gm = fmaxf(gm, sm.sred[w2]);
    float fa[NWV];
    float L = 0.f;
#pragma unroll
    for (int w2 = 0; w2 < NWV; ++w2) {
      const float lw = sm.sred[8 + w2];
      fa[w2] = (lw > 0.f) ? __expf(sm.sred[w2] - gm) : 0.f;
      L = fmaf(fa[w2], lw, L);
    }
    float* pb = part + (size_t)blockIdx.x * PSTRIDE;
#pragma unroll
    for (int j = 0; j < 3; ++j) {
      float4 a = make_float4(0.f, 0.f, 0.f, 0.f);
#pragma unroll
      for (int w2 = 0; w2 < NWV; ++w2) {
        const float4 t = sm.sacc[w2][lane + 64 * j];
        a.x = fmaf(fa[w2], t.x, a.x);
        a.y = fmaf(fa[w2], t.y, a.y);
        a.z = fmaf(fa[w2], t.z, a.z);
        a.w = fmaf(fa[w2], t.w, a.w);
      }
      *(float4*)(pb + ACC_OFF + 4 * (lane + 64 * j)) = a;
    }
    if (lane == 0) { pb[0] = gm; pb[1] = L; }
  }
}

// distributed combine: block c<192 produces float4 column c of the result.
__device__ void combine_phase(const float* __restrict__ P, float* dstA, float* dstB,
                              SMem& sm) {
  const int tid = threadIdx.x;
  const int lane = tid & 63;
  const int wv = tid >> 6;
  const int blk = blockIdx.x;
  if (blk >= H4) return;
  const float mt = (tid < NB) ? P[(size_t)tid * PSTRIDE] : -INFINITY;
  const float wm = wave_max(mt);
  if (lane == 0) sm.sred[wv] = wm;
  __syncthreads();
  float gm = sm.sred[0];
#pragma unroll
  for (int w2 = 1; w2 < NWV; ++w2) gm = fmaxf(gm, sm.sred[w2]);
  float contrib = 0.f;
  float4 a = make_float4(0.f, 0.f, 0.f, 0.f);
  if (tid < NB) {
    const float lb = P[(size_t)tid * PSTRIDE + 1];
    const float e = (lb > 0.f) ? __expf(mt - gm) : 0.f;
    contrib = e * lb;
    const float4 t = ((const float4*)(P + (size_t)tid * PSTRIDE + ACC_OFF))[blk];
    a = make_float4(e * t.x, e * t.y, e * t.z, e * t.w);
  }
  const float ws = wave_sum(contrib);
  a.x = wave_sum(a.x); a.y = wave_sum(a.y); a.z = wave_sum(a.z); a.w = wave_sum(a.w);
  if (lane == 0) { sm.sred[8 + wv] = ws; ((float4*)sm.sacc)[wv] = a; }  // slots disjoint from sred[0..7]
  __syncthreads();
  if (tid == 0) {
    float L = 0.f;
    float4 s = make_float4(0.f, 0.f, 0.f, 0.f);
#pragma unroll
    for (int w2 = 0; w2 < NWV; ++w2) {
      L += sm.sred[8 + w2];
      const float4 t = ((float4*)sm.sacc)[w2];
      s.x += t.x; s.y += t.y; s.z += t.z; s.w += t.w;
    }
    const float inv = 1.f / L;
    const float4 r = make_float4(s.x * inv, s.y * inv, s.z * inv, s.w * inv);
    ((float4*)dstA)[blk] = r;
    if (dstB) ((float4*)dstB)[blk] = r;
  }
}

__global__ __launch_bounds__(NT) void k_all(
    const float4* __restrict__ fact4, const float4* __restrict__ ep4,
    const float4* __restrict__ W4, float* __restrict__ out,
    float4* __restrict__ pmax4, float* __restrict__ q,
    float* __restrict__ epws, float* __restrict__ v,
    float* __restrict__ pm, float* __restrict__ pn, int N, int M) {
  cg::grid_group grid = cg::this_grid();
  __shared__ SMem sm;
  const int tid = threadIdx.x;
  const int lane = tid & 63;
  const int wv = tid >> 6;
  const int blk = blockIdx.x;

  // ---- phase 1: colmax partials over fact (+ block 0 zeroes q)
  {
    if (blk == 0) { q[tid] = 0.f; if (tid < H - NT) q[NT + tid] = 0.f; }
    const int rpb = (N + NB - 1) / NB;  // 128
    const int n0 = blk * rpb;
    const int n1 = min(N, n0 + rpb);
    float4* flat = (float4*)sm.sacc;
    if (tid < 2 * H4) {
      const int c = tid % H4;
      const int h = tid / H4;  // 0/1: two rows in flight
      float4 m = make_float4(-INFINITY, -INFINITY, -INFINITY, -INFINITY);
      for (int n = n0 + h; n < n1; n += 2) m = f4max(m, fact4[(size_t)n * H4 + c]);
      flat[h * H4 + c] = m;
    }
    __syncthreads();
    if (tid < H4) pmax4[(size_t)blk * H4 + tid] = f4max(flat[tid], flat[H4 + tid]);
  }
  grid.sync();

  // ---- phase 2: fQ (column max over 256 partials) fused with q = fQ@W chunk.
  // 48 blocks own 16 k's each; atomicAdd into q (zeroed in phase 1).
  if (blk < 48) {
    const int g0 = blk * 4;           // float4 column groups g0..g0+3
    const int g = tid >> 7;           // 0..3
    const int p = tid & 127;
    float4 m = f4max(pmax4[(size_t)p * H4 + g0 + g],
                     pmax4[(size_t)(p + 128) * H4 + g0 + g]);
    m.x = wave_max(m.x); m.y = wave_max(m.y); m.z = wave_max(m.z); m.w = wave_max(m.w);
    if (lane == 0) ((float4*)sm.sacc)[wv] = m;  // waves 2g, 2g+1 hold group g
    __syncthreads();
    if (tid < 16) {
      const int gg = tid >> 2, cc = tid & 3;
      const float4 u = ((float4*)sm.sacc)[2 * gg];
      const float4 w2 = ((float4*)sm.sacc)[2 * gg + 1];
      sm.sfq[tid] = fmaxf(((const float*)&u)[cc], ((const float*)&w2)[cc]);
    }
    __syncthreads();
    if (tid < H4) {
      float4 acc = make_float4(0.f, 0.f, 0.f, 0.f);
#pragma unroll 4
      for (int kk = 0; kk < 16; ++kk) {
        const float f = sm.sfq[kk];
        const float4 w = W4[(size_t)(blk * 16 + kk) * H4 + tid];
        acc.x = fmaf(f, w.x, acc.x);
        acc.y = fmaf(f, w.y, acc.y);
        acc.z = fmaf(f, w.z, acc.z);
        acc.w = fmaf(f, w.w, acc.w);
      }
      atomicAdd(&q[4 * tid + 0], acc.x);
      atomicAdd(&q[4 * tid + 1], acc.y);
      atomicAdd(&q[4 * tid + 2], acc.z);
      atomicAdd(&q[4 * tid + 3], acc.w);
    }
  }
  grid.sync();

  // ---- phase 3: ep online-softmax pass (scores ep@q)
  pass_phase(ep4, q, pm, M, sm);
  grid.sync();

  // ---- phase 4: combine -> elements_p_ (epws + out[H..2H))
  combine_phase(pm, epws, out + H, sm);
  grid.sync();

  // ---- phase 5: v = W @ elements_p_^T (one wave per row, 96 blocks)
  {
    const int gw = blk * NWV + wv;
    if (gw < H) {
      float s = 0.f;
#pragma unroll
      for (int j = 0; j < 3; ++j) {
        const float4 w = W4[(size_t)gw * H4 + lane + 64 * j];
        const float4 e = ((const float4*)epws)[lane + 64 * j];
        s = fmaf(w.x, e.x, s);
        s = fmaf(w.y, e.y, s);
        s = fmaf(w.z, e.z, s);
        s = fmaf(w.w, e.w, s);
      }
      s = wave_sum(s);
      if (lane == 0) v[gw] = s;
    }
  }
  grid.sync();

  // ---- phase 6: fact online-softmax pass (scores fact@v)
  pass_phase(fact4, v, pn, N, sm);
  grid.sync();

  // ---- phase 7: combine -> fact_ (out[0..H))
  combine_phase(pn, out, nullptr, sm);
}

extern "C" void kernel_launch(void* const* d_in, const int* in_sizes, int n_in,
                              void* d_out, int out_size, void* d_ws, size_t ws_size,
                              hipStream_t stream) {
  const float4* fact4 = (const float4*)d_in[0];  // [N,H]
  const float4* ep4   = (const float4*)d_in[1];  // [M,H]
  const float4* W4    = (const float4*)d_in[2];  // [H,H]
  float* out = (float*)d_out;
  int N = in_sizes[0] / H;
  int M = in_sizes[1] / H;

  float* wsf = (float*)d_ws;
  float* q     = wsf;                               // 768
  float* epws  = wsf + 768;                         // 768
  float* v     = wsf + 1536;                        // 768
  float4* pmax4 = (float4*)(wsf + 2304);            // NB*768 floats
  float* pm    = wsf + 2304 + NB * H;               // NB*772
  float* pn    = pm + (size_t)NB * PSTRIDE;         // NB*772

  void* args[] = {&fact4, &ep4, &W4, &out, &pmax4, &q, &epws, &v, &pm, &pn, &N, &M};
  hipLaunchCooperativeKernel((void*)k_all, dim3(NB), dim3(NT), args, 0, stream);
}

// Round 5
// 307.007 us; speedup vs baseline: 1.2458x; 1.2458x over previous
//
#include <hip/hip_runtime.h>
#include <math.h>

// N=32768, M=4096, H=768 fp32.
// out[0..768)=fact_, out[768..1536)=elements_p_.
// Reassociation: (X@W)@y^T == X@(W@y^T) -> matvecs only, never a GEMM.
// R4 post-mortem: cooperative grid.sync ~30us each on ROCm -> kernel 251us. Reverted.
// R5: 3 graph nodes. colmax -> ep(prologue fQ,q + stream + last-block combine + v)
//     -> fact(stream + last-block combine). Arrival counters zeroed by k_colmax.
// HBM floor ~114 MB (fact L3-resident for pass 2, per R4 FETCH_SIZE) ~= 18 us.

#define H 768
#define H4 192
#define PSTRIDE 772   // partial: [0]=m, [1]=L, [2..3]=pad, [4..772)=acc[768]
#define ACC_OFF 4
#define B1 256        // colmax blocks
#define B2 48         // ep blocks
#define B3 256        // fact blocks

__device__ __forceinline__ float wave_max(float x) {
#pragma unroll
  for (int o = 32; o; o >>= 1) x = fmaxf(x, __shfl_xor(x, o, 64));
  return x;
}
__device__ __forceinline__ float wave_sum(float x) {
#pragma unroll
  for (int o = 32; o; o >>= 1) x += __shfl_xor(x, o, 64);
  return x;
}
__device__ __forceinline__ float4 f4max(float4 a, float4 b) {
  return make_float4(fmaxf(a.x, b.x), fmaxf(a.y, b.y), fmaxf(a.z, b.z), fmaxf(a.w, b.w));
}

// --- K1: colmax partials over fact; block 0 zeroes the two arrival counters.
__global__ __launch_bounds__(192) void k_colmax(const float4* __restrict__ x4,
                                                float4* __restrict__ pmax4, int N,
                                                unsigned int* __restrict__ cnts) {
  if (blockIdx.x == 0 && threadIdx.x < 2) cnts[threadIdx.x] = 0u;
  const int t = threadIdx.x;
  const int rpb = (N + B1 - 1) / B1;  // 128
  const int n0 = blockIdx.x * rpb;
  const int n1 = min(N, n0 + rpb);
  float4 m = make_float4(-INFINITY, -INFINITY, -INFINITY, -INFINITY);
#pragma unroll 8
  for (int n = n0; n < n1; ++n) m = f4max(m, x4[(size_t)n * H4 + t]);
  pmax4[(size_t)blockIdx.x * H4 + t] = m;
}

// --- K2: [prologue] fQ = colmax(pmax), q = fQ^T W (in LDS) ->
//         [stream] online-softmax over ep rows -> block partial ->
//         [last-block] combine -> elements_p_ (out+H) ; v = W @ ep_^T -> global.
__global__ __launch_bounds__(512) void k_ep(const float4* __restrict__ ep4,
                                            const float4* __restrict__ W4,
                                            const float4* __restrict__ pmax4,
                                            float* __restrict__ part, int M,
                                            unsigned int* __restrict__ cnt,
                                            float* __restrict__ out_ep,
                                            float* __restrict__ v) {
  const int tid = threadIdx.x;
  const int lane = tid & 63;
  const int wv = tid >> 6;
  __shared__ float4 sacc[8][H4];   // wave partials / phase scratch
  __shared__ float4 fq4[H4];       // fQ; reused as ep_ in the tail
  __shared__ float4 qarr4[H4];     // q
  __shared__ float sred[16];
  __shared__ float se[B2];
  __shared__ unsigned int s_last;

  // ---- prologue A: fQ[c] = max_p pmax[p][c]  (2 groups x 192 float4-cols)
  if (tid < 2 * H4) {
    const int g = tid / H4, c = tid % H4;
    float4 m = make_float4(-INFINITY, -INFINITY, -INFINITY, -INFINITY);
#pragma unroll 8
    for (int p = g; p < B1; p += 2) m = f4max(m, pmax4[(size_t)p * H4 + c]);
    ((float4*)sacc)[g * H4 + c] = m;
  }
  __syncthreads();
  if (tid < H4) fq4[tid] = f4max(((float4*)sacc)[tid], ((float4*)sacc)[H4 + tid]);
  __syncthreads();
  // ---- prologue B: q[h] = sum_k fQ[k]*W[k,h]  (2 groups split the k range)
  if (tid < 2 * H4) {
    const int g = tid / H4, c = tid % H4;
    const float* fq = (const float*)fq4;
    float4 a = make_float4(0.f, 0.f, 0.f, 0.f);
#pragma unroll 4
    for (int k = g * 384; k < g * 384 + 384; ++k) {
      const float f = fq[k];
      const float4 w = W4[(size_t)k * H4 + c];
      a.x = fmaf(f, w.x, a.x);
      a.y = fmaf(f, w.y, a.y);
      a.z = fmaf(f, w.z, a.z);
      a.w = fmaf(f, w.w, a.w);
    }
    ((float4*)sacc)[g * H4 + c] = a;
  }
  __syncthreads();
  if (tid < H4) {
    const float4 a = ((float4*)sacc)[tid], b = ((float4*)sacc)[H4 + tid];
    qarr4[tid] = make_float4(a.x + b.x, a.y + b.y, a.z + b.z, a.w + b.w);
  }
  __syncthreads();

  // ---- stream: online softmax over this block's ep rows (scores ep@q)
  {
    float4 wr[3];
#pragma unroll
    for (int j = 0; j < 3; ++j) wr[j] = qarr4[lane + 64 * j];
    const int nw = B2 * 8;
    const int gw = blockIdx.x * 8 + wv;
    const int rpw = (M + nw - 1) / nw;
    const int r0 = gw * rpw;
    const int r1 = min(M, r0 + rpw);
    float mrun = -INFINITY, l = 0.f;
    float4 acc[3];
#pragma unroll
    for (int j = 0; j < 3; ++j) acc[j] = make_float4(0.f, 0.f, 0.f, 0.f);
    for (int r = r0; r < r1; ++r) {
      const float4* row = ep4 + (size_t)r * H4;
      float4 x[3];
      float s = 0.f;
#pragma unroll
      for (int j = 0; j < 3; ++j) {
        x[j] = row[lane + 64 * j];
        s = fmaf(x[j].x, wr[j].x, s);
        s = fmaf(x[j].y, wr[j].y, s);
        s = fmaf(x[j].z, wr[j].z, s);
        s = fmaf(x[j].w, wr[j].w, s);
      }
      s = wave_sum(s);
      const float mn = fmaxf(mrun, s);
      const float esc = __expf(mrun - mn);
      const float p = __expf(s - mn);
      l = fmaf(l, esc, p);
#pragma unroll
      for (int j = 0; j < 3; ++j) {
        acc[j].x = fmaf(acc[j].x, esc, p * x[j].x);
        acc[j].y = fmaf(acc[j].y, esc, p * x[j].y);
        acc[j].z = fmaf(acc[j].z, esc, p * x[j].z);
        acc[j].w = fmaf(acc[j].w, esc, p * x[j].w);
      }
      mrun = mn;
    }
    if (lane == 0) { sred[wv] = mrun; sred[8 + wv] = l; }
#pragma unroll
    for (int j = 0; j < 3; ++j) sacc[wv][lane + 64 * j] = acc[j];
    __syncthreads();
    if (wv == 0) {
      float gm = -INFINITY;
#pragma unroll
      for (int w2 = 0; w2 < 8; ++w2) gm = fmaxf(gm, sred[w2]);
      float fa[8];
      float L = 0.f;
#pragma unroll
      for (int w2 = 0; w2 < 8; ++w2) {
        const float lw = sred[8 + w2];
        fa[w2] = (lw > 0.f) ? __expf(sred[w2] - gm) : 0.f;
        L = fmaf(fa[w2], lw, L);
      }
      float* pb = part + (size_t)blockIdx.x * PSTRIDE;
#pragma unroll
      for (int j = 0; j < 3; ++j) {
        float4 a = make_float4(0.f, 0.f, 0.f, 0.f);
#pragma unroll
        for (int w2 = 0; w2 < 8; ++w2) {
          const float4 t = sacc[w2][lane + 64 * j];
          a.x = fmaf(fa[w2], t.x, a.x);
          a.y = fmaf(fa[w2], t.y, a.y);
          a.z = fmaf(fa[w2], t.z, a.z);
          a.w = fmaf(fa[w2], t.w, a.w);
        }
        *(float4*)(pb + ACC_OFF + 4 * (lane + 64 * j)) = a;
      }
      if (lane == 0) { pb[0] = gm; pb[1] = L; }
    }
  }

  // ---- arrival (R3-proven)
  __syncthreads();
  if (tid == 0) {
    __threadfence();
    s_last = atomicAdd(cnt, 1u);
  }
  __syncthreads();
  if (s_last != (unsigned)(B2 - 1)) return;
  __threadfence();

  // ---- combine B2 partials -> ep_ ; then v = W @ ep_^T
  {
    const float* P = part;
    float gm = -INFINITY;
    for (int b = tid; b < B2; b += 512) gm = fmaxf(gm, P[(size_t)b * PSTRIDE]);
    gm = wave_max(gm);
    if (lane == 0) sred[wv] = gm;
    __syncthreads();
    gm = sred[0];
#pragma unroll
    for (int w2 = 1; w2 < 8; ++w2) gm = fmaxf(gm, sred[w2]);
    float L = 0.f;
    for (int b = tid; b < B2; b += 512) {
      const float m = P[(size_t)b * PSTRIDE];
      const float lb = P[(size_t)b * PSTRIDE + 1];
      const float e = (lb > 0.f) ? __expf(m - gm) : 0.f;
      se[b] = e;
      L = fmaf(e, lb, L);
    }
    L = wave_sum(L);
    if (lane == 0) sred[8 + wv] = L;
    __syncthreads();
    float Lt = sred[8];
#pragma unroll
    for (int w2 = 1; w2 < 8; ++w2) Lt += sred[8 + w2];
    if (tid < H4) {
      float4 a = make_float4(0.f, 0.f, 0.f, 0.f);
#pragma unroll 4
      for (int b = 0; b < B2; ++b) {
        const float e = se[b];
        const float4 t = *(const float4*)(P + (size_t)b * PSTRIDE + ACC_OFF + 4 * tid);
        a.x = fmaf(e, t.x, a.x);
        a.y = fmaf(e, t.y, a.y);
        a.z = fmaf(e, t.z, a.z);
        a.w = fmaf(e, t.w, a.w);
      }
      const float inv = 1.f / Lt;
      const float4 r = make_float4(a.x * inv, a.y * inv, a.z * inv, a.w * inv);
      ((float4*)out_ep)[tid] = r;
      fq4[tid] = r;  // ep_ for the v matvec
    }
    __syncthreads();
    // v[i] = dot(W[i,:], ep_) ; one wave per row, 4 rows in flight for ILP
    float4 er[3];
#pragma unroll
    for (int j = 0; j < 3; ++j) er[j] = fq4[lane + 64 * j];
    for (int i0 = wv * 96; i0 < wv * 96 + 96; i0 += 4) {
      float s0 = 0.f, s1 = 0.f, s2 = 0.f, s3 = 0.f;
#pragma unroll
      for (int j = 0; j < 3; ++j) {
        const float4 e = er[j];
        const float4 w0 = W4[(size_t)(i0 + 0) * H4 + lane + 64 * j];
        const float4 w1 = W4[(size_t)(i0 + 1) * H4 + lane + 64 * j];
        const float4 w2 = W4[(size_t)(i0 + 2) * H4 + lane + 64 * j];
        const float4 w3 = W4[(size_t)(i0 + 3) * H4 + lane + 64 * j];
        s0 = fmaf(w0.x, e.x, s0); s0 = fmaf(w0.y, e.y, s0);
        s0 = fmaf(w0.z, e.z, s0); s0 = fmaf(w0.w, e.w, s0);
        s1 = fmaf(w1.x, e.x, s1); s1 = fmaf(w1.y, e.y, s1);
        s1 = fmaf(w1.z, e.z, s1); s1 = fmaf(w1.w, e.w, s1);
        s2 = fmaf(w2.x, e.x, s2); s2 = fmaf(w2.y, e.y, s2);
        s2 = fmaf(w2.z, e.z, s2); s2 = fmaf(w2.w, e.w, s2);
        s3 = fmaf(w3.x, e.x, s3); s3 = fmaf(w3.y, e.y, s3);
        s3 = fmaf(w3.z, e.z, s3); s3 = fmaf(w3.w, e.w, s3);
      }
#pragma unroll
      for (int o = 32; o; o >>= 1) {
        s0 += __shfl_xor(s0, o, 64);
        s1 += __shfl_xor(s1, o, 64);
        s2 += __shfl_xor(s2, o, 64);
        s3 += __shfl_xor(s3, o, 64);
      }
      if (lane == 0) ((float4*)v)[i0 >> 2] = make_float4(s0, s1, s2, s3);
    }
  }
}

// --- K3: fact online-softmax pass (scores fact@v) + last-block combine -> out.
__global__ __launch_bounds__(512) void k_fact(const float4* __restrict__ X4,
                                              const float* __restrict__ wvec,
                                              float* __restrict__ part, int R,
                                              unsigned int* __restrict__ cnt,
                                              float* __restrict__ outp) {
  const int tid = threadIdx.x;
  const int lane = tid & 63;
  const int wv = tid >> 6;
  __shared__ float sm[8], sl[8];
  __shared__ float4 sacc[8][H4];
  __shared__ unsigned int s_last;

  {
    float4 wr[3];
#pragma unroll
    for (int j = 0; j < 3; ++j) wr[j] = ((const float4*)wvec)[lane + 64 * j];
    const int nw = B3 * 8;
    const int gw = blockIdx.x * 8 + wv;
    const int rpw = (R + nw - 1) / nw;
    const int r0 = gw * rpw;
    const int r1 = min(R, r0 + rpw);
    float mrun = -INFINITY, l = 0.f;
    float4 acc[3];
#pragma unroll
    for (int j = 0; j < 3; ++j) acc[j] = make_float4(0.f, 0.f, 0.f, 0.f);
    for (int r = r0; r < r1; ++r) {
      const float4* row = X4 + (size_t)r * H4;
      float4 x[3];
      float s = 0.f;
#pragma unroll
      for (int j = 0; j < 3; ++j) {
        x[j] = row[lane + 64 * j];
        s = fmaf(x[j].x, wr[j].x, s);
        s = fmaf(x[j].y, wr[j].y, s);
        s = fmaf(x[j].z, wr[j].z, s);
        s = fmaf(x[j].w, wr[j].w, s);
      }
      s = wave_sum(s);
      const float mn = fmaxf(mrun, s);
      const float esc = __expf(mrun - mn);
      const float p = __expf(s - mn);
      l = fmaf(l, esc, p);
#pragma unroll
      for (int j = 0; j < 3; ++j) {
        acc[j].x = fmaf(acc[j].x, esc, p * x[j].x);
        acc[j].y = fmaf(acc[j].y, esc, p * x[j].y);
        acc[j].z = fmaf(acc[j].z, esc, p * x[j].z);
        acc[j].w = fmaf(acc[j].w, esc, p * x[j].w);
      }
      mrun = mn;
    }
    if (lane == 0) { sm[wv] = mrun; sl[wv] = l; }
#pragma unroll
    for (int j = 0; j < 3; ++j) sacc[wv][lane + 64 * j] = acc[j];
    __syncthreads();
    if (wv == 0) {
      float gm = -INFINITY;
#pragma unroll
      for (int w2 = 0; w2 < 8; ++w2) gm = fmaxf(gm, sm[w2]);
      float fa[8];
      float L = 0.f;
#pragma unroll
      for (int w2 = 0; w2 < 8; ++w2) {
        fa[w2] = (sl[w2] > 0.f) ? __expf(sm[w2] - gm) : 0.f;
        L = fmaf(fa[w2], sl[w2], L);
      }
      float* pb = part + (size_t)blockIdx.x * PSTRIDE;
#pragma unroll
      for (int j = 0; j < 3; ++j) {
        float4 a = make_float4(0.f, 0.f, 0.f, 0.f);
#pragma unroll
        for (int w2 = 0; w2 < 8; ++w2) {
          const float4 t = sacc[w2][lane + 64 * j];
          a.x = fmaf(fa[w2], t.x, a.x);
          a.y = fmaf(fa[w2], t.y, a.y);
          a.z = fmaf(fa[w2], t.z, a.z);
          a.w = fmaf(fa[w2], t.w, a.w);
        }
        *(float4*)(pb + ACC_OFF + 4 * (lane + 64 * j)) = a;
      }
      if (lane == 0) { pb[0] = gm; pb[1] = L; }
    }
  }

  __syncthreads();
  if (tid == 0) {
    __threadfence();
    s_last = atomicAdd(cnt, 1u);
  }
  __syncthreads();
  if (s_last != (unsigned)(B3 - 1)) return;
  __threadfence();

  {  // combine B3 partials -> out
    __shared__ float sred[16];
    const float* P = part;
    float gm = -INFINITY;
    for (int b = tid; b < B3; b += 512) gm = fmaxf(gm, P[(size_t)b * PSTRIDE]);
    gm = wave_max(gm);
    if (lane == 0) sred[wv] = gm;
    __syncthreads();
    gm = sred[0];
#pragma unroll
    for (int w2 = 1; w2 < 8; ++w2) gm = fmaxf(gm, sred[w2]);
    __syncthreads();
    float L = 0.f;
    for (int b = tid; b < B3; b += 512) {
      const float m = P[(size_t)b * PSTRIDE];
      const float lb = P[(size_t)b * PSTRIDE + 1];
      L = fmaf((lb > 0.f) ? __expf(m - gm) : 0.f, lb, L);
    }
    L = wave_sum(L);
    if (lane == 0) sred[8 + wv] = L;
    // weighted acc: wave wv takes b = wv, wv+8, ...
    float4 a[3];
#pragma unroll
    for (int j = 0; j < 3; ++j) a[j] = make_float4(0.f, 0.f, 0.f, 0.f);
    for (int b = wv; b < B3; b += 8) {
      const float m = P[(size_t)b * PSTRIDE];
      const float lb = P[(size_t)b * PSTRIDE + 1];
      const float e = (lb > 0.f) ? __expf(m - gm) : 0.f;
      const float4* pa = (const float4*)(P + (size_t)b * PSTRIDE + ACC_OFF);
#pragma unroll
      for (int j = 0; j < 3; ++j) {
        const float4 t = pa[lane + 64 * j];
        a[j].x = fmaf(e, t.x, a[j].x);
        a[j].y = fmaf(e, t.y, a[j].y);
        a[j].z = fmaf(e, t.z, a[j].z);
        a[j].w = fmaf(e, t.w, a[j].w);
      }
    }
#pragma unroll
    for (int j = 0; j < 3; ++j) sacc[wv][lane + 64 * j] = a[j];
    __syncthreads();
    if (tid < H4) {
      float4 s = sacc[0][tid];
#pragma unroll
      for (int w2 = 1; w2 < 8; ++w2) {
        const float4 t = sacc[w2][tid];
        s.x += t.x; s.y += t.y; s.z += t.z; s.w += t.w;
      }
      float Lt = sred[8];
#pragma unroll
      for (int w2 = 1; w2 < 8; ++w2) Lt += sred[8 + w2];
      const float inv = 1.f / Lt;
      ((float4*)outp)[tid] = make_float4(s.x * inv, s.y * inv, s.z * inv, s.w * inv);
    }
  }
}

extern "C" void kernel_launch(void* const* d_in, const int* in_sizes, int n_in,
                              void* d_out, int out_size, void* d_ws, size_t ws_size,
                              hipStream_t stream) {
  const float4* fact4 = (const float4*)d_in[0];  // [N,H]
  const float4* ep4   = (const float4*)d_in[1];  // [M,H]
  const float4* W4    = (const float4*)d_in[2];  // [H,H]
  float* out = (float*)d_out;
  const int N = in_sizes[0] / H;
  const int M = in_sizes[1] / H;

  float* wsf = (float*)d_ws;
  unsigned int* cnts = (unsigned int*)d_ws;      // [0]=ep arrival, [1]=fact arrival
  float* v = wsf + 4;                            // 768 floats (16B-aligned)
  float4* pmax4 = (float4*)(wsf + 4 + H);        // B1*768 floats
  float* pm = wsf + 4 + H + B1 * H;              // B2*772
  float* pn = pm + (size_t)B2 * PSTRIDE;         // B3*772

  k_colmax<<<B1, 192, 0, stream>>>(fact4, pmax4, N, cnts);
  k_ep<<<B2, 512, 0, stream>>>(ep4, W4, pmax4, pm, M, cnts + 0, out + H, v);
  k_fact<<<B3, 512, 0, stream>>>(fact4, v, pn, N, cnts + 1, out);
}

// Round 6
// 285.063 us; speedup vs baseline: 1.3417x; 1.0770x over previous
//
#include <hip/hip_runtime.h>
#include <math.h>

// N=32768, M=4096, H=768 fp32.
// out[0..768)=fact_, out[768..1536)=elements_p_.
// Reassociation: (X@W)@y^T == X@(W@y^T) -> matvecs only, never a GEMM.
// R5 post-mortem: k_ep's per-block full-W prologue was 114us (48 blocks x 2.4MB
// serial L3 reads). R6: 4 nodes; q via split-k k_q (R3-proven, 3us); k_ep is a
// pure 256-block stream; v lives in k_ep's last-block tail (W L3-hot).
// HBM floor ~115 MB (fact L3-resident on 2nd pass, per R4 FETCH) ~= 18 us.

#define H 768
#define H4 192
#define PSTRIDE 772   // partial: [0]=m, [1]=L, [2..3]=pad, [4..772)=acc[768]
#define ACC_OFF 4
#define B1 256        // colmax blocks
#define BQ 48         // k_q blocks (16 k's each)
#define B2 256        // ep blocks
#define B3 256        // fact blocks

__device__ __forceinline__ float wave_max(float x) {
#pragma unroll
  for (int o = 32; o; o >>= 1) x = fmaxf(x, __shfl_xor(x, o, 64));
  return x;
}
__device__ __forceinline__ float wave_sum(float x) {
#pragma unroll
  for (int o = 32; o; o >>= 1) x += __shfl_xor(x, o, 64);
  return x;
}
__device__ __forceinline__ float4 f4max(float4 a, float4 b) {
  return make_float4(fmaxf(a.x, b.x), fmaxf(a.y, b.y), fmaxf(a.z, b.z), fmaxf(a.w, b.w));
}

struct SMem {
  float4 sacc[8][H4];  // 24.6 KB wave partials / combine scratch
  float sred[16];
  float4 sep[H4];      // ep_ copy for the v tail (k_ep only)
};

// ---- shared streaming pass: online-softmax weighted row-sum -> part[blk]
__device__ __forceinline__ void stream_pass(const float4* __restrict__ X4,
                                            const float* __restrict__ wvec,
                                            float* __restrict__ part, int R,
                                            int NBk, SMem& sm) {
  const int tid = threadIdx.x;
  const int lane = tid & 63;
  const int wv = tid >> 6;
  float4 wr[3];
#pragma unroll
  for (int j = 0; j < 3; ++j) wr[j] = ((const float4*)wvec)[lane + 64 * j];
  const int nw = NBk * 8;
  const int gw = blockIdx.x * 8 + wv;
  const int rpw = (R + nw - 1) / nw;
  const int r0 = gw * rpw;
  const int r1 = min(R, r0 + rpw);
  float mrun = -INFINITY, l = 0.f;
  float4 acc[3];
#pragma unroll
  for (int j = 0; j < 3; ++j) acc[j] = make_float4(0.f, 0.f, 0.f, 0.f);
  for (int r = r0; r < r1; ++r) {
    const float4* row = X4 + (size_t)r * H4;
    float4 x[3];
    float s = 0.f;
#pragma unroll
    for (int j = 0; j < 3; ++j) {
      x[j] = row[lane + 64 * j];
      s = fmaf(x[j].x, wr[j].x, s);
      s = fmaf(x[j].y, wr[j].y, s);
      s = fmaf(x[j].z, wr[j].z, s);
      s = fmaf(x[j].w, wr[j].w, s);
    }
    s = wave_sum(s);
    const float mn = fmaxf(mrun, s);
    const float esc = __expf(mrun - mn);  // exp(-inf)=0 on first row
    const float p = __expf(s - mn);
    l = fmaf(l, esc, p);
#pragma unroll
    for (int j = 0; j < 3; ++j) {
      acc[j].x = fmaf(acc[j].x, esc, p * x[j].x);
      acc[j].y = fmaf(acc[j].y, esc, p * x[j].y);
      acc[j].z = fmaf(acc[j].z, esc, p * x[j].z);
      acc[j].w = fmaf(acc[j].w, esc, p * x[j].w);
    }
    mrun = mn;
  }
  if (lane == 0) { sm.sred[wv] = mrun; sm.sred[8 + wv] = l; }
#pragma unroll
  for (int j = 0; j < 3; ++j) sm.sacc[wv][lane + 64 * j] = acc[j];
  __syncthreads();
  if (wv == 0) {
    float gm = -INFINITY;
#pragma unroll
    for (int w2 = 0; w2 < 8; ++w2) gm = fmaxf(gm, sm.sred[w2]);
    float fa[8];
    float L = 0.f;
#pragma unroll
    for (int w2 = 0; w2 < 8; ++w2) {
      const float lw = sm.sred[8 + w2];
      fa[w2] = (lw > 0.f) ? __expf(sm.sred[w2] - gm) : 0.f;
      L = fmaf(fa[w2], lw, L);
    }
    float* pb = part + (size_t)blockIdx.x * PSTRIDE;
#pragma unroll
    for (int j = 0; j < 3; ++j) {
      float4 a = make_float4(0.f, 0.f, 0.f, 0.f);
#pragma unroll
      for (int w2 = 0; w2 < 8; ++w2) {
        const float4 t = sm.sacc[w2][lane + 64 * j];
        a.x = fmaf(fa[w2], t.x, a.x);
        a.y = fmaf(fa[w2], t.y, a.y);
        a.z = fmaf(fa[w2], t.z, a.z);
        a.w = fmaf(fa[w2], t.w, a.w);
      }
      *(float4*)(pb + ACC_OFF + 4 * (lane + 64 * j)) = a;
    }
    if (lane == 0) { pb[0] = gm; pb[1] = L; }
  }
}

// ---- shared last-block combine: NBk partials -> normalized result
__device__ __forceinline__ void combine_all(const float* __restrict__ P, int NBk,
                                            float* __restrict__ dst, bool keep_lds,
                                            SMem& sm) {
  const int tid = threadIdx.x;
  const int lane = tid & 63;
  const int wv = tid >> 6;
  float gm = -INFINITY;
  for (int b = tid; b < NBk; b += 512) gm = fmaxf(gm, P[(size_t)b * PSTRIDE]);
  gm = wave_max(gm);
  if (lane == 0) sm.sred[wv] = gm;
  __syncthreads();
  gm = sm.sred[0];
#pragma unroll
  for (int w2 = 1; w2 < 8; ++w2) gm = fmaxf(gm, sm.sred[w2]);
  __syncthreads();
  float L = 0.f;
  for (int b = tid; b < NBk; b += 512) {
    const float m = P[(size_t)b * PSTRIDE];
    const float lb = P[(size_t)b * PSTRIDE + 1];
    L = fmaf((lb > 0.f) ? __expf(m - gm) : 0.f, lb, L);
  }
  L = wave_sum(L);
  if (lane == 0) sm.sred[8 + wv] = L;
  // weighted acc: wave wv takes b = wv, wv+8, ...
  float4 a[3];
#pragma unroll
  for (int j = 0; j < 3; ++j) a[j] = make_float4(0.f, 0.f, 0.f, 0.f);
  for (int b = wv; b < NBk; b += 8) {
    const float m = P[(size_t)b * PSTRIDE];
    const float lb = P[(size_t)b * PSTRIDE + 1];
    const float e = (lb > 0.f) ? __expf(m - gm) : 0.f;
    const float4* pa = (const float4*)(P + (size_t)b * PSTRIDE + ACC_OFF);
#pragma unroll
    for (int j = 0; j < 3; ++j) {
      const float4 t = pa[lane + 64 * j];
      a[j].x = fmaf(e, t.x, a[j].x);
      a[j].y = fmaf(e, t.y, a[j].y);
      a[j].z = fmaf(e, t.z, a[j].z);
      a[j].w = fmaf(e, t.w, a[j].w);
    }
  }
#pragma unroll
  for (int j = 0; j < 3; ++j) sm.sacc[wv][lane + 64 * j] = a[j];
  __syncthreads();
  if (tid < H4) {
    float4 s = sm.sacc[0][tid];
#pragma unroll
    for (int w2 = 1; w2 < 8; ++w2) {
      const float4 t = sm.sacc[w2][tid];
      s.x += t.x; s.y += t.y; s.z += t.z; s.w += t.w;
    }
    float Lt = sm.sred[8];
#pragma unroll
    for (int w2 = 1; w2 < 8; ++w2) Lt += sm.sred[8 + w2];
    const float inv = 1.f / Lt;
    const float4 r = make_float4(s.x * inv, s.y * inv, s.z * inv, s.w * inv);
    ((float4*)dst)[tid] = r;
    if (keep_lds) sm.sep[tid] = r;
  }
}

// --- K1: colmax partials over fact; block 0 zeroes counters + q.
__global__ __launch_bounds__(192) void k_colmax(const float4* __restrict__ x4,
                                                float4* __restrict__ pmax4, int N,
                                                unsigned int* __restrict__ cnts,
                                                float* __restrict__ q) {
  const int t = threadIdx.x;
  if (blockIdx.x == 0) {
    if (t < 2) cnts[t] = 0u;
#pragma unroll
    for (int j = 0; j < 4; ++j) q[t + 192 * j] = 0.f;
  }
  const int rpb = (N + B1 - 1) / B1;  // 128
  const int n0 = blockIdx.x * rpb;
  const int n1 = min(N, n0 + rpb);
  float4 m = make_float4(-INFINITY, -INFINITY, -INFINITY, -INFINITY);
#pragma unroll 8
  for (int n = n0; n < n1; ++n) m = f4max(m, x4[(size_t)n * H4 + t]);
  pmax4[(size_t)blockIdx.x * H4 + t] = m;
}

// --- K2: split-k q. Block b owns k in [16b,16b+16): reduces those 16 pmax
// columns, then q[h] += sum_k fQ[k]*W[k,h] via atomicAdd. (R3-proven, ~3us.)
__global__ __launch_bounds__(192) void k_q(const float4* __restrict__ W4,
                                           const float* __restrict__ pmax,
                                           float* __restrict__ q, int B) {
  const int tid = threadIdx.x;
  const int k0 = blockIdx.x * 16;
  __shared__ float sA[12][16];
  __shared__ float fQl[16];
  {
    const int col = tid & 15;
    const int grp = tid >> 4;  // 0..11
    float m = -INFINITY;
    for (int p = grp; p < B; p += 12) m = fmaxf(m, pmax[(size_t)p * H + k0 + col]);
    sA[grp][col] = m;
    __syncthreads();
    if (tid < 16) {
      float mm = sA[0][tid];
#pragma unroll
      for (int g = 1; g < 12; ++g) mm = fmaxf(mm, sA[g][tid]);
      fQl[tid] = mm;
    }
    __syncthreads();
  }
  float4 acc = make_float4(0.f, 0.f, 0.f, 0.f);
#pragma unroll 4
  for (int kk = 0; kk < 16; ++kk) {
    const float f = fQl[kk];
    const float4 w = W4[(size_t)(k0 + kk) * H4 + tid];
    acc.x = fmaf(f, w.x, acc.x);
    acc.y = fmaf(f, w.y, acc.y);
    acc.z = fmaf(f, w.z, acc.z);
    acc.w = fmaf(f, w.w, acc.w);
  }
  atomicAdd(&q[4 * tid + 0], acc.x);
  atomicAdd(&q[4 * tid + 1], acc.y);
  atomicAdd(&q[4 * tid + 2], acc.z);
  atomicAdd(&q[4 * tid + 3], acc.w);
}

// --- K3: ep stream (scores ep@q) + last-block combine -> elements_p_ + v.
__global__ __launch_bounds__(512) void k_ep(const float4* __restrict__ ep4,
                                            const float4* __restrict__ W4,
                                            const float* __restrict__ q,
                                            float* __restrict__ part, int M,
                                            unsigned int* __restrict__ cnt,
                                            float* __restrict__ out_ep,
                                            float* __restrict__ v) {
  const int tid = threadIdx.x;
  const int lane = tid & 63;
  const int wv = tid >> 6;
  __shared__ SMem sm;
  __shared__ unsigned int s_last;

  stream_pass(ep4, q, part, M, B2, sm);

  __syncthreads();
  if (tid == 0) {
    __threadfence();
    s_last = atomicAdd(cnt, 1u);
  }
  __syncthreads();
  if (s_last != (unsigned)(B2 - 1)) return;
  __threadfence();

  combine_all(part, B2, out_ep, true, sm);
  __syncthreads();

  // v[i] = dot(W[i,:], ep_); one wave per row, 4 rows in flight (W is L3-hot).
  float4 er[3];
#pragma unroll
  for (int j = 0; j < 3; ++j) er[j] = sm.sep[lane + 64 * j];
  for (int i0 = wv * 96; i0 < wv * 96 + 96; i0 += 4) {
    float s0 = 0.f, s1 = 0.f, s2 = 0.f, s3 = 0.f;
#pragma unroll
    for (int j = 0; j < 3; ++j) {
      const float4 e = er[j];
      const float4 w0 = W4[(size_t)(i0 + 0) * H4 + lane + 64 * j];
      const float4 w1 = W4[(size_t)(i0 + 1) * H4 + lane + 64 * j];
      const float4 w2 = W4[(size_t)(i0 + 2) * H4 + lane + 64 * j];
      const float4 w3 = W4[(size_t)(i0 + 3) * H4 + lane + 64 * j];
      s0 = fmaf(w0.x, e.x, s0); s0 = fmaf(w0.y, e.y, s0);
      s0 = fmaf(w0.z, e.z, s0); s0 = fmaf(w0.w, e.w, s0);
      s1 = fmaf(w1.x, e.x, s1); s1 = fmaf(w1.y, e.y, s1);
      s1 = fmaf(w1.z, e.z, s1); s1 = fmaf(w1.w, e.w, s1);
      s2 = fmaf(w2.x, e.x, s2); s2 = fmaf(w2.y, e.y, s2);
      s2 = fmaf(w2.z, e.z, s2); s2 = fmaf(w2.w, e.w, s2);
      s3 = fmaf(w3.x, e.x, s3); s3 = fmaf(w3.y, e.y, s3);
      s3 = fmaf(w3.z, e.z, s3); s3 = fmaf(w3.w, e.w, s3);
    }
#pragma unroll
    for (int o = 32; o; o >>= 1) {
      s0 += __shfl_xor(s0, o, 64);
      s1 += __shfl_xor(s1, o, 64);
      s2 += __shfl_xor(s2, o, 64);
      s3 += __shfl_xor(s3, o, 64);
    }
    if (lane == 0) ((float4*)v)[i0 >> 2] = make_float4(s0, s1, s2, s3);
  }
}

// --- K4: fact stream (scores fact@v, L3-resident) + last-block combine -> out.
__global__ __launch_bounds__(512) void k_fact(const float4* __restrict__ X4,
                                              const float* __restrict__ v,
                                              float* __restrict__ part, int R,
                                              unsigned int* __restrict__ cnt,
                                              float* __restrict__ outp) {
  const int tid = threadIdx.x;
  __shared__ SMem sm;
  __shared__ unsigned int s_last;

  stream_pass(X4, v, part, R, B3, sm);

  __syncthreads();
  if (tid == 0) {
    __threadfence();
    s_last = atomicAdd(cnt, 1u);
  }
  __syncthreads();
  if (s_last != (unsigned)(B3 - 1)) return;
  __threadfence();

  combine_all(part, B3, outp, false, sm);
}

extern "C" void kernel_launch(void* const* d_in, const int* in_sizes, int n_in,
                              void* d_out, int out_size, void* d_ws, size_t ws_size,
                              hipStream_t stream) {
  const float4* fact4 = (const float4*)d_in[0];  // [N,H]
  const float4* ep4   = (const float4*)d_in[1];  // [M,H]
  const float4* W4    = (const float4*)d_in[2];  // [H,H]
  float* out = (float*)d_out;
  const int N = in_sizes[0] / H;
  const int M = in_sizes[1] / H;

  float* wsf = (float*)d_ws;
  unsigned int* cnts = (unsigned int*)d_ws;      // [0]=ep, [1]=fact arrival
  float* q = wsf + 4;                            // 768 (16B aligned)
  float* v = wsf + 4 + H;                        // 768
  float* pmaxf = wsf + 4 + 2 * H;                // B1*768
  float* pm = pmaxf + (size_t)B1 * H;            // B2*772
  float* pn = pm + (size_t)B2 * PSTRIDE;         // B3*772

  k_colmax<<<B1, 192, 0, stream>>>(fact4, (float4*)pmaxf, N, cnts, q);
  k_q<<<BQ, 192, 0, stream>>>(W4, pmaxf, q, B1);
  k_ep<<<B2, 512, 0, stream>>>(ep4, W4, q, pm, M, cnts + 0, out + H, v);
  k_fact<<<B3, 512, 0, stream>>>(fact4, v, pn, N, cnts + 1, out);
}